// Round 3
// baseline (190.754 us; speedup 1.0000x reference)
//
#include <hip/hip_runtime.h>

// B=8, S=2048, IN=1024, H=1024
//   q  = vec @ wq_w^T + wq_b            [B,S,H]
//   ret= relu(q_b^T q_b) per batch      [B,H,H]   (registers only)
//   out= ret @ lin_w + lin_b            [B,H]
//
// Pipeline:
//   prep:       out init + vec/wq fp32->bf16 (one launch)
//   gemm_q3:    256x256 tile, BK=64, DEPTH-2 pipeline: B triple-buffered LDS
//               (global_load_lds, vmcnt waited at 2-tile distance), A
//               register-staged (L2-hot) into single LDS slot. bf16 MFMA,
//               fp8 e4m3 epilogue.
//   syrk_half8: fp8, BK=128, double-buffered 2-phase, batch->XCD swizzle
//               (each batch's 2 MiB qT8 slice is L2-resident on one XCD).

typedef short     bf16x8 __attribute__((ext_vector_type(8)));
typedef unsigned short u16x8 __attribute__((ext_vector_type(8)));
typedef float     f32x4 __attribute__((ext_vector_type(4)));
typedef long long i64;

#define FENCE asm volatile("" ::: "memory")
#define BARR  do { FENCE; __builtin_amdgcn_s_barrier(); FENCE; } while (0)
#define VMCNT(N) asm volatile("s_waitcnt vmcnt(" #N ")" ::: "memory")
#define LGKM0 asm volatile("s_waitcnt lgkmcnt(0)" ::: "memory")

__device__ inline unsigned short f2bf(float f) {
  unsigned int u = __float_as_uint(f);
  u += 0x7fffu + ((u >> 16) & 1u);   // RNE
  return (unsigned short)(u >> 16);
}

__device__ inline u16x8 pack8(float4 a, float4 b) {
  u16x8 r;
  r[0] = f2bf(a.x); r[1] = f2bf(a.y); r[2] = f2bf(a.z); r[3] = f2bf(a.w);
  r[4] = f2bf(b.x); r[5] = f2bf(b.y); r[6] = f2bf(b.z); r[7] = f2bf(b.w);
  return r;
}

__device__ inline unsigned char f2fp8(float v) {
  int pk = __builtin_amdgcn_cvt_pk_fp8_f32(v, v, 0, false);  // RNE, OCP e4m3
  return (unsigned char)(pk & 0xff);
}

__device__ inline void async16(void* lds, const void* g) {
  __builtin_amdgcn_global_load_lds(
      (const __attribute__((address_space(1))) void*)g,
      (__attribute__((address_space(3))) void*)lds,
      16, 0, 0);
}

// One launch: vec cvt (blocks 0..8191), wq cvt (blocks 8192..8703), out init
__global__ __launch_bounds__(256) void prep(
    const float* __restrict__ vec, unsigned short* __restrict__ vecbf,
    const float* __restrict__ wq,  unsigned short* __restrict__ wqbf,
    const float* __restrict__ lin_b, float* __restrict__ out)
{
  const int gid = blockIdx.x * 256 + threadIdx.x;
  if (blockIdx.x < 8192) {
    const float4* s = (const float4*)(vec + (size_t)gid * 8);
    float4 a = s[0], b = s[1];
    *(u16x8*)(vecbf + (size_t)gid * 8) = pack8(a, b);
    if (gid < 8192) out[gid] = lin_b[0];
  } else {
    const int i = gid - 8192 * 256;   // 0..131071
    const float4* s = (const float4*)(wq + (size_t)i * 8);
    float4 a = s[0], b = s[1];
    *(u16x8*)(wqbf + (size_t)i * 8) = pack8(a, b);
  }
}

__global__ void init_out(float* __restrict__ out, const float* __restrict__ lin_b) {
  int i = blockIdx.x * 256 + threadIdx.x;
  if (i < 8192) out[i] = lin_b[0];
}

// ------- gemm_q3: 256x256 tile, BK=64, depth-2 pipeline -------
// C[m][n] = sum_k A[m][k]*B[n][k];  A=wqbf [1024,1024], B=vecbf [16384,1024].
// 512 thr = 8 waves (2M x 4N).
// B: LDS triple-buffer (3 x 32 KiB), staged kt+2 via global_load_lds.
//    In-order vmcnt: per iter issue order is [A-regs(kt+2), B(kt+2)]; steady
//    outstanding before the wait = {B(kt),A(kt+1),B(kt+1),A(kt+2),B(kt+2)}=20;
//    VMCNT(12) completes the oldest 8 = B(kt) [2-tile distance] + A(kt+1),
//    leaving both next tiles' loads in flight (never drains to 0).
// A: register-staged (2 banks x 4 uint4, statically unrolled), ds_written to a
//    single 32 KiB slot after the consume-barrier. A is 2 MiB shared by all
//    blocks -> L2-hot -> 1-tile distance suffices.
// LDS = 96 + 32 = 128 KiB; VGPR ~250 (launch_bounds caps at 256).
__global__ __launch_bounds__(512, 2) void gemm_q3(
    const unsigned short* __restrict__ A, const unsigned short* __restrict__ Bm,
    const float* __restrict__ bias, unsigned char* __restrict__ qT8)
{
  __shared__ unsigned short As[256 * 64];      // 32 KiB, single slot
  __shared__ unsigned short Bs[3][256 * 64];   // 96 KiB, triple buffer

  const int m0 = blockIdx.y * 256;
  const int n0 = blockIdx.x * 256;
  const int t    = threadIdx.x;          // 0..511
  const int lane = t & 63;
  const int wave = t >> 6;               // 0..7
  const int wm2  = (wave >> 2) * 64;     // 0,64
  const int wn2  = (wave & 3) * 32;      // 0..96
  const int quad = lane >> 4;
  const int lrow = lane & 15;

  // staging geometry: thread t covers rows {p*64+srow}, LDS 16B slot t&7;
  // pre-swizzled global chunk (t&7)^(srow&7) so ds_read applies the same XOR.
  const int srow = t >> 3;                         // 0..63
  const int gch  = (t & 7) ^ (srow & 7);
  const int lsl  = srow * 64 + (t & 7) * 8;        // LDS offset (shorts), +p*4096
  const unsigned short* gA = A  + (size_t)(m0 + srow) * 1024 + gch * 8;
  const unsigned short* gB = Bm + (size_t)(n0 + srow) * 1024 + gch * 8;

#define STAGE_B3(SLOT, KT) do { \
  _Pragma("unroll") for (int p = 0; p < 4; ++p) \
    async16(&Bs[SLOT][p * 4096 + lsl], gB + (size_t)p * 65536 + (KT) * 64); \
} while (0)

#define LOAD_A3(RB, KT) do { \
  _Pragma("unroll") for (int p = 0; p < 4; ++p) \
    RB[p] = *reinterpret_cast<const uint4*>(gA + (size_t)p * 65536 + (KT) * 64); \
} while (0)

#define WRITE_A3(RB) do { \
  _Pragma("unroll") for (int p = 0; p < 4; ++p) \
    *reinterpret_cast<uint4*>(&As[p * 4096 + lsl]) = RB[p]; \
  LGKM0; \
} while (0)

#define LDA_HALF(MH) do { \
  _Pragma("unroll") for (int f = 0; f < 4; ++f) \
  _Pragma("unroll") for (int kk = 0; kk < 2; ++kk) \
    a_[f][kk] = *(const bf16x8*)&As[((MH)*128 + wm2 + f*16 + lrow)*64 + \
                                    (((kk*4 + quad) ^ (lrow & 7)) * 8)]; \
} while (0)

#define LDB_HALF(S, NH, BREG) do { \
  _Pragma("unroll") for (int g = 0; g < 2; ++g) \
  _Pragma("unroll") for (int kk = 0; kk < 2; ++kk) \
    BREG[g][kk] = *(const bf16x8*)&Bs[S][((NH)*128 + wn2 + g*16 + lrow)*64 + \
                                         (((kk*4 + quad) ^ (lrow & 7)) * 8)]; \
} while (0)

#define MFMAQ(MH, NH, BREG) do { \
  __builtin_amdgcn_s_setprio(1); \
  _Pragma("unroll") for (int kk = 0; kk < 2; ++kk) \
  _Pragma("unroll") for (int f = 0; f < 4; ++f) \
  _Pragma("unroll") for (int g = 0; g < 2; ++g) \
    acc[MH][f][NH][g] = __builtin_amdgcn_mfma_f32_16x16x32_bf16( \
        a_[f][kk], BREG[g][kk], acc[MH][f][NH][g], 0, 0, 0); \
  __builtin_amdgcn_s_setprio(0); \
} while (0)

// full tile compute from B-slot S (A in its single slot)
#define COMPUTE(S) do { \
  LDA_HALF(0); \
  LDB_HALF(S, 0, b0_); \
  MFMAQ(0, 0, b0_); \
  LDB_HALF(S, 1, b1_); \
  MFMAQ(0, 1, b1_); \
  LDA_HALF(1); \
  MFMAQ(1, 0, b0_); \
  MFMAQ(1, 1, b1_); \
} while (0)

  f32x4 acc[2][4][2][2];
#pragma unroll
  for (int i = 0; i < 2; ++i)
#pragma unroll
    for (int f = 0; f < 4; ++f)
#pragma unroll
      for (int j = 0; j < 2; ++j)
#pragma unroll
        for (int g = 0; g < 2; ++g) acc[i][f][j][g] = (f32x4){0.f, 0.f, 0.f, 0.f};

  bf16x8 a_[4][2], b0_[2][2], b1_[2][2];
  uint4 ra0[4], ra1[4];

  // ---- prologue: issue A0,B0,A1,B1 (16 outstanding); write A0 ----
  LOAD_A3(ra0, 0);
  STAGE_B3(0, 0);
  LOAD_A3(ra1, 1);
  STAGE_B3(1, 1);
  VMCNT(12);          // A(0) regs complete
  WRITE_A3(ra0);

  // ---- main loop: 7 double-iterations cover kt = 0..13 ----
  int srd = 0;        // B read slot (kt % 3)
  int snx = 2;        // B stage slot ((kt+2) % 3)
#pragma unroll 1
  for (int kt = 0; kt < 14; kt += 2) {
    // even sub-iter kt: load A(kt+2)->bank0, stage B(kt+2); compute tile kt
    LOAD_A3(ra0, kt + 2);
    STAGE_B3(snx, kt + 2);
    VMCNT(12);         // completes B(kt) [D=2] and A(kt+1) regs
    BARR;
    COMPUTE(srd);
    BARR;
    WRITE_A3(ra1);     // A(kt+1) -> LDS
    srd = (srd == 2) ? 0 : srd + 1;
    snx = (snx == 2) ? 0 : snx + 1;

    // odd sub-iter kt+1: load A(kt+3)->bank1, stage B(kt+3); compute kt+1
    LOAD_A3(ra1, kt + 3);
    STAGE_B3(snx, kt + 3);
    VMCNT(12);         // completes B(kt+1) [D=2] and A(kt+2) regs
    BARR;
    COMPUTE(srd);
    BARR;
    WRITE_A3(ra0);     // A(kt+2) -> LDS
    srd = (srd == 2) ? 0 : srd + 1;
    snx = (snx == 2) ? 0 : snx + 1;
  }

  // ---- peel kt = 14: no new issues; outstanding = {B14, A15, B15} ----
  VMCNT(4);            // completes B(14) and A(15) regs, leaves B(15)
  BARR;
  COMPUTE(srd);
  BARR;
  WRITE_A3(ra1);       // A(15) -> LDS
  srd = (srd == 2) ? 0 : srd + 1;

  // ---- peel kt = 15 ----
  VMCNT(0);            // B(15) complete
  BARR;
  COMPUTE(srd);

  // ---- epilogue: bias + fp8 quantize, write qT8[m][n] ----
#pragma unroll
  for (int mh = 0; mh < 2; ++mh)
#pragma unroll
    for (int f = 0; f < 4; ++f)
#pragma unroll
      for (int r = 0; r < 4; ++r) {
        const int m = m0 + mh * 128 + wm2 + f * 16 + quad * 4 + r;
        const float bv = bias[m];
        unsigned char* row = qT8 + (size_t)m * 16384 + n0;
#pragma unroll
        for (int nh = 0; nh < 2; ++nh)
#pragma unroll
          for (int g = 0; g < 2; ++g)
            row[nh * 128 + wn2 + g * 16 + lrow] = f2fp8(acc[mh][f][nh][g][r] + bv);
      }

#undef STAGE_B3
#undef LOAD_A3
#undef WRITE_A3
#undef LDA_HALF
#undef LDB_HALF
#undef MFMAQ
#undef COMPUTE
}

// ------- fallback gemm_q (fused fp32->bf16 inline), used if ws too small -------
__global__ __launch_bounds__(256) void gemm_q_fused(
    const float* __restrict__ Wq, const float* __restrict__ V,
    const float* __restrict__ bias, unsigned char* __restrict__ qT8)
{
  __shared__ unsigned short As[128 * 32];
  __shared__ unsigned short Bs[128 * 32];

  const int m0 = blockIdx.y * 128;
  const int n0 = blockIdx.x * 128;
  const int t    = threadIdx.x;
  const int lane = t & 63;
  const int wave = t >> 6;
  const int wm = (wave >> 1) * 64;
  const int wn = (wave & 1) * 64;
  const int quad = lane >> 4;
  const int lrow = lane & 15;

  const int sr = t >> 1;
  const int sc = (t & 1) << 4;
  const float* gA = Wq + (size_t)(m0 + sr) * 1024 + sc;
  const float* gB = V  + (size_t)(n0 + sr) * 1024 + sc;

  f32x4 acc[4][4];
#pragma unroll
  for (int i = 0; i < 4; ++i)
#pragma unroll
    for (int j = 0; j < 4; ++j) acc[i][j] = (f32x4){0.f, 0.f, 0.f, 0.f};

  for (int k0 = 0; k0 < 1024; k0 += 32) {
    const float4* a4 = (const float4*)(gA + k0);
    const float4* b4 = (const float4*)(gB + k0);
    float4 av0 = a4[0], av1 = a4[1], av2 = a4[2], av3 = a4[3];
    float4 bv0 = b4[0], bv1 = b4[1], bv2 = b4[2], bv3 = b4[3];
    *(u16x8*)&As[sr * 32 + sc]     = pack8(av0, av1);
    *(u16x8*)&As[sr * 32 + sc + 8] = pack8(av2, av3);
    *(u16x8*)&Bs[sr * 32 + sc]     = pack8(bv0, bv1);
    *(u16x8*)&Bs[sr * 32 + sc + 8] = pack8(bv2, bv3);
    __syncthreads();

    bf16x8 af[4], bfr[4];
#pragma unroll
    for (int i = 0; i < 4; ++i)
      af[i] = *(const bf16x8*)&As[(wm + i * 16 + lrow) * 32 + quad * 8];
#pragma unroll
    for (int j = 0; j < 4; ++j)
      bfr[j] = *(const bf16x8*)&Bs[(wn + j * 16 + lrow) * 32 + quad * 8];
#pragma unroll
    for (int i = 0; i < 4; ++i)
#pragma unroll
      for (int j = 0; j < 4; ++j)
        acc[i][j] = __builtin_amdgcn_mfma_f32_16x16x32_bf16(af[i], bfr[j], acc[i][j], 0, 0, 0);
    __syncthreads();
  }

#pragma unroll
  for (int i = 0; i < 4; ++i) {
    const int mb = m0 + wm + i * 16 + quad * 4;
#pragma unroll
    for (int r = 0; r < 4; ++r) {
      const float bv = bias[mb + r];
#pragma unroll
      for (int j = 0; j < 4; ++j) {
        const int n = n0 + wn + j * 16 + lrow;
        qT8[(size_t)(mb + r) * 16384 + n] = f2fp8(acc[i][j][r] + bv);
      }
    }
  }
}

// ---------- syrk_half8: fp8, BK=128, dbuf 2-phase, batch->XCD swizzle ----------
// qT8 fp8 [1024][16384]; batch bb cols [bb*2048,+2048) = 2 MiB -> fits ONE
// XCD's 4 MiB L2. blockIdx.x in [0,576): bb = bid&7 so all 72 blocks of batch
// bb land on XCD bb (dispatch round-robins consecutive blocks across XCDs) ->
// after warmup all qT8 reads are L2 hits. id2=bid>>3: pair=id2>>1 (ty<=tx over
// 8 128-tiles), yh=id2&1. FULL K=2048 (relu nonlinear -> K-split illegal).
__global__ __launch_bounds__(256) void syrk_half8(
    const unsigned char* __restrict__ qT8, const float* __restrict__ W,
    float* __restrict__ out)
{
  __shared__ unsigned char As[2][128 * 128];  // 32 KB
  __shared__ unsigned char Bs[2][64 * 128];   // 16 KB

  const int bb   = blockIdx.x & 7;
  const int id2  = blockIdx.x >> 3;           // 0..71
  const int pair = id2 >> 1;
  const int yh   = id2 & 1;
  int tx = 0;
  while ((tx + 1) * (tx + 2) / 2 <= pair) ++tx;
  const int ty = pair - tx * (tx + 1) / 2;
  const int x0 = tx * 128;
  const int y0 = ty * 128 + yh * 64;
  const bool diag = (tx == ty);

  const int t    = threadIdx.x;
  const int lane = t & 63;
  const int wave = t >> 6;
  const int wm = (wave >> 1) * 64;   // x offset of wave: 0 or 64
  const int wn = (wave & 1) * 32;    // y offset of wave: 0 or 32
  const int quad = lane >> 4;
  const int lrow = lane & 15;

  // staging: issue p covers rows p*32 + (t>>3); global 16B chunk
  // (t&7)^(row&7) lands at LDS slot t&7.
  const int srow = t >> 3;                              // 0..31
  const int g16  = (t & 7) ^ (srow & 7);
  const size_t cb = (size_t)bb * 2048 + g16 * 16;
  const unsigned char* gA = qT8 + (size_t)(x0 + srow) * 16384 + cb;
  const unsigned char* gB = qT8 + (size_t)(y0 + srow) * 16384 + cb;

#define SSTAGE(SLOT, KT) do { \
  _Pragma("unroll") for (int p = 0; p < 4; ++p) \
    async16(&As[SLOT][p * 4096 + t * 16], gA + (size_t)p * 32 * 16384 + (KT) * 128); \
  _Pragma("unroll") for (int p = 0; p < 2; ++p) \
    async16(&Bs[SLOT][p * 4096 + t * 16], gB + (size_t)p * 32 * 16384 + (KT) * 128); \
} while (0)

#define SYRK_COMPUTE(S) do { \
  _Pragma("unroll") for (int kk = 0; kk < 4; ++kk) { \
    const int c = kk * 4 + quad; \
    const int off = (((c >> 1) ^ (lrow & 7)) << 4) + (c & 1) * 8; \
    i64 af[4], bfr[2]; \
    _Pragma("unroll") for (int i = 0; i < 4; ++i) \
      af[i] = *(const i64*)&As[S][(wm + i * 16 + lrow) * 128 + off]; \
    _Pragma("unroll") for (int j = 0; j < 2; ++j) \
      bfr[j] = *(const i64*)&Bs[S][(wn + j * 16 + lrow) * 128 + off]; \
    _Pragma("unroll") for (int i = 0; i < 4; ++i) \
      _Pragma("unroll") for (int j = 0; j < 2; ++j) \
        acc[i][j] = __builtin_amdgcn_mfma_f32_16x16x32_fp8_fp8(af[i], bfr[j], acc[i][j], 0, 0, 0); \
  } \
} while (0)

  f32x4 acc[4][2];
#pragma unroll
  for (int i = 0; i < 4; ++i)
#pragma unroll
    for (int j = 0; j < 2; ++j) acc[i][j] = (f32x4){0.f, 0.f, 0.f, 0.f};

  // prologue: stage tile 0 -> slot 0 (6 insts outstanding)
  SSTAGE(0, 0);

#pragma unroll 1
  for (int kt = 0; kt < 15; ++kt) {
    const int s = kt & 1;
    SSTAGE(s ^ 1, kt + 1);   // 6 insts; tile t's 6 may still be in flight
    VMCNT(6);                // completes tile t, leaves tile t+1 in flight
    BARR;                    // all waves' tile-t stages now visible
    SYRK_COMPUTE(s);
    BARR;                    // reads done before next iter overwrites slot s
  }

  // peeled kt=15 (slot 1): drain
  VMCNT(0);
  BARR;
  SYRK_COMPUTE(1);

#undef SSTAGE
#undef SYRK_COMPUTE

  float* ob = out + bb * 1024;

  // row pass: out[x] += sum_y relu(C[x,y]) * W[y]   (partial over this y-half)
  float wv[2];
#pragma unroll
  for (int j = 0; j < 2; ++j) wv[j] = W[y0 + wn + j * 16 + lrow];

#pragma unroll
  for (int i = 0; i < 4; ++i) {
#pragma unroll
    for (int r = 0; r < 4; ++r) {
      float p = 0.f;
#pragma unroll
      for (int j = 0; j < 2; ++j) {
        float v = acc[i][j][r];
        v = v > 0.f ? v : 0.f;
        p += v * wv[j];
      }
#pragma unroll
      for (int off = 1; off < 16; off <<= 1) p += __shfl_xor(p, off, 64);
      if (lrow == 0)
        atomicAdd(&ob[x0 + wm + i * 16 + quad * 4 + r], p);
    }
  }

  // col pass (off-diagonal pairs only): out[y] += sum_x relu(C[x,y]) * W[x]
  if (!diag) {
    float wx[4][4];
#pragma unroll
    for (int i = 0; i < 4; ++i)
#pragma unroll
      for (int r = 0; r < 4; ++r)
        wx[i][r] = W[x0 + wm + i * 16 + quad * 4 + r];

#pragma unroll
    for (int j = 0; j < 2; ++j) {
      float pc = 0.f;
#pragma unroll
      for (int i = 0; i < 4; ++i)
#pragma unroll
        for (int r = 0; r < 4; ++r) {
          float v = acc[i][j][r];
          v = v > 0.f ? v : 0.f;
          pc += v * wx[i][r];
        }
      pc += __shfl_xor(pc, 16, 64);
      pc += __shfl_xor(pc, 32, 64);
      if (quad == 0)
        atomicAdd(&ob[y0 + wn + j * 16 + lrow], pc);
    }
  }
}

extern "C" void kernel_launch(void* const* d_in, const int* in_sizes, int n_in,
                              void* d_out, int out_size, void* d_ws, size_t ws_size,
                              hipStream_t stream) {
  const float* vec   = (const float*)d_in[0];  // [8,2048,1024]
  const float* wq_w  = (const float*)d_in[1];  // [1024,1024]
  const float* wq_b  = (const float*)d_in[2];  // [1024]
  const float* lin_w = (const float*)d_in[3];  // [1,1024]
  const float* lin_b = (const float*)d_in[4];  // [1]
  float* out = (float*)d_out;                  // [8,1024]

  unsigned char* qT8 = (unsigned char*)d_ws;                       // 16 MiB
  const size_t need = (size_t)(16 + 32 + 2) * 1024 * 1024;

  if (ws_size >= need) {
    unsigned short* vecbf = (unsigned short*)((char*)d_ws + (size_t)16 * 1024 * 1024); // 32 MiB
    unsigned short* wqbf  = vecbf + (size_t)16 * 1024 * 1024;                          // 2 MiB
    prep<<<dim3(8192 + 512), dim3(256), 0, stream>>>(vec, vecbf, wq_w, wqbf, lin_b, out);
    gemm_q3<<<dim3(64, 4), dim3(512), 0, stream>>>(wqbf, vecbf, wq_b, qT8);
  } else {
    init_out<<<dim3(32), dim3(256), 0, stream>>>(out, lin_b);
    gemm_q_fused<<<dim3(128, 8), dim3(256), 0, stream>>>(wq_w, vec, wq_b, qT8);
  }
  syrk_half8<<<dim3(576), dim3(256), 0, stream>>>(qT8, lin_w, out);
}

// Round 4
// 164.233 us; speedup vs baseline: 1.1615x; 1.1615x over previous
//
#include <hip/hip_runtime.h>

// B=8, S=2048, IN=1024, H=1024
//   q  = vec @ wq_w^T + wq_b            [B,S,H]
//   ret= relu(q_b^T q_b) per batch      [B,H,H]   (registers only)
//   out= ret @ lin_w + lin_b            [B,H]
//
// Pipeline:
//   prep:       out init + vec/wq fp32->bf16 (one launch)
//   gemm_q8p:   256x256 tile, BK=64, 4-phase counted-vmcnt schedule (round-1
//               verified structure) + bijective XCD swizzle so each XCD's L2
//               holds its blocks' A+B panels (6 MB working set vs 16 MB).
//   syrk_half8: fp8, BK=128, double-buffered 2-phase counted-vmcnt,
//               batch->XCD swizzle (2 MiB qT8 slice L2-resident per XCD).
//
// Hard-won constraints (rounds 0-3):
//   - ALL LDS staging via global_load_lds (ds_write staging => 2.26M bank
//     conflicts, -55% on gemm; r3).
//   - vmcnt distance beyond ~2 phases buys nothing (r1=r2=r3 within noise).
//   - relu nonlinear -> syrk K-split illegal; full K per block.

typedef short     bf16x8 __attribute__((ext_vector_type(8)));
typedef unsigned short u16x8 __attribute__((ext_vector_type(8)));
typedef float     f32x4 __attribute__((ext_vector_type(4)));
typedef long long i64;

#define FENCE asm volatile("" ::: "memory")
#define BARR  do { FENCE; __builtin_amdgcn_s_barrier(); FENCE; } while (0)
#define VMCNT(N) asm volatile("s_waitcnt vmcnt(" #N ")" ::: "memory")

__device__ inline unsigned short f2bf(float f) {
  unsigned int u = __float_as_uint(f);
  u += 0x7fffu + ((u >> 16) & 1u);   // RNE
  return (unsigned short)(u >> 16);
}

__device__ inline u16x8 pack8(float4 a, float4 b) {
  u16x8 r;
  r[0] = f2bf(a.x); r[1] = f2bf(a.y); r[2] = f2bf(a.z); r[3] = f2bf(a.w);
  r[4] = f2bf(b.x); r[5] = f2bf(b.y); r[6] = f2bf(b.z); r[7] = f2bf(b.w);
  return r;
}

__device__ inline unsigned char f2fp8(float v) {
  int pk = __builtin_amdgcn_cvt_pk_fp8_f32(v, v, 0, false);  // RNE, OCP e4m3
  return (unsigned char)(pk & 0xff);
}

__device__ inline void async16(void* lds, const void* g) {
  __builtin_amdgcn_global_load_lds(
      (const __attribute__((address_space(1))) void*)g,
      (__attribute__((address_space(3))) void*)lds,
      16, 0, 0);
}

// One launch: vec cvt (blocks 0..8191), wq cvt (blocks 8192..8703), out init
__global__ __launch_bounds__(256) void prep(
    const float* __restrict__ vec, unsigned short* __restrict__ vecbf,
    const float* __restrict__ wq,  unsigned short* __restrict__ wqbf,
    const float* __restrict__ lin_b, float* __restrict__ out)
{
  const int gid = blockIdx.x * 256 + threadIdx.x;
  if (blockIdx.x < 8192) {
    const float4* s = (const float4*)(vec + (size_t)gid * 8);
    float4 a = s[0], b = s[1];
    *(u16x8*)(vecbf + (size_t)gid * 8) = pack8(a, b);
    if (gid < 8192) out[gid] = lin_b[0];
  } else {
    const int i = gid - 8192 * 256;   // 0..131071
    const float4* s = (const float4*)(wq + (size_t)i * 8);
    float4 a = s[0], b = s[1];
    *(u16x8*)(wqbf + (size_t)i * 8) = pack8(a, b);
  }
}

__global__ void init_out(float* __restrict__ out, const float* __restrict__ lin_b) {
  int i = blockIdx.x * 256 + threadIdx.x;
  if (i < 8192) out[i] = lin_b[0];
}

// ------- gemm_q8p: 256x256 tile, BK=64, 4-phase counted-vmcnt (round-1) -------
// C[m][n] = sum_k A[m][k]*B[n][k];  A=wqbf [1024,1024], B=vecbf [16384,1024].
// 512 thr = 8 waves (2M x 4N).  LDS = 2 slots x (A 32K + B 32K) = 128 KiB.
// XCD swizzle: 256 blocks; bid = y*64+x dispatched round-robin over 8 XCDs.
// Remap so XCD k gets x-chunk [8k,8k+8) x all 4 y: per-XCD L2 working set =
// A 2 MB (8x reuse) + B 4 MB (4x reuse), instead of 16 MB of distinct B.
__global__ __launch_bounds__(512, 2) void gemm_q8p(
    const unsigned short* __restrict__ A, const unsigned short* __restrict__ Bm,
    const float* __restrict__ bias, unsigned char* __restrict__ qT8)
{
  __shared__ unsigned short As[2][256 * 64];   // 64 KiB
  __shared__ unsigned short Bs[2][256 * 64];   // 64 KiB

  // bijective XCD remap (256 = 8 XCD x 32)
  const int bid = blockIdx.y * 64 + blockIdx.x;   // 0..255
  const int xcd = bid & 7;
  const int idx = bid >> 3;                       // 0..31
  const int m0 = (idx & 3) * 256;                 // 4 M-tiles
  const int n0 = (xcd * 8 + (idx >> 2)) * 256;    // 64 N-tiles, chunked per XCD

  const int t    = threadIdx.x;          // 0..511
  const int lane = t & 63;
  const int wave = t >> 6;               // 0..7
  const int wm2  = (wave >> 2) * 64;     // 0,64
  const int wn2  = (wave & 3) * 32;      // 0..96
  const int quad = lane >> 4;
  const int lrow = lane & 15;

  // staging: thread t covers row (t>>3) of each 64-row group, LDS 16B slot t&7;
  // pre-swizzled global chunk (t&7)^(row&7) so ds_read applies the same XOR.
  const int srow = t >> 3;                         // 0..63
  const int gch  = (t & 7) ^ (srow & 7);
  const unsigned short* gA = A  + (size_t)(m0 + srow) * 1024 + gch * 8;
  const unsigned short* gB = Bm + (size_t)(n0 + srow) * 1024 + gch * 8;

#define STAGE_A(SLOT, H, KT) do { \
  _Pragma("unroll") for (int p = 0; p < 2; ++p) \
    async16(&As[SLOT][((H)*128 + p*64)*64 + t*8], \
            gA + (size_t)((H)*128 + p*64)*1024 + (KT)*64); \
} while (0)

#define STAGE_B(SLOT, H, KT) do { \
  _Pragma("unroll") for (int p = 0; p < 2; ++p) \
    async16(&Bs[SLOT][((H)*128 + p*64)*64 + t*8], \
            gB + (size_t)((H)*128 + p*64)*1024 + (KT)*64); \
} while (0)

#define LDA_HALF(S, MH) do { \
  _Pragma("unroll") for (int f = 0; f < 4; ++f) \
  _Pragma("unroll") for (int kk = 0; kk < 2; ++kk) \
    a_[f][kk] = *(const bf16x8*)&As[S][((MH)*128 + wm2 + f*16 + lrow)*64 + \
                                       (((kk*4 + quad) ^ (lrow & 7)) * 8)]; \
} while (0)

#define LDB_HALF(S, NH, BREG) do { \
  _Pragma("unroll") for (int g = 0; g < 2; ++g) \
  _Pragma("unroll") for (int kk = 0; kk < 2; ++kk) \
    BREG[g][kk] = *(const bf16x8*)&Bs[S][((NH)*128 + wn2 + g*16 + lrow)*64 + \
                                         (((kk*4 + quad) ^ (lrow & 7)) * 8)]; \
} while (0)

#define MFMAQ(MH, NH, BREG) do { \
  __builtin_amdgcn_s_setprio(1); \
  _Pragma("unroll") for (int kk = 0; kk < 2; ++kk) \
  _Pragma("unroll") for (int f = 0; f < 4; ++f) \
  _Pragma("unroll") for (int g = 0; g < 2; ++g) \
    acc[MH][f][NH][g] = __builtin_amdgcn_mfma_f32_16x16x32_bf16( \
        a_[f][kk], BREG[g][kk], acc[MH][f][NH][g], 0, 0, 0); \
  __builtin_amdgcn_s_setprio(0); \
} while (0)

  f32x4 acc[2][4][2][2];
#pragma unroll
  for (int i = 0; i < 2; ++i)
#pragma unroll
    for (int f = 0; f < 4; ++f)
#pragma unroll
      for (int j = 0; j < 2; ++j)
#pragma unroll
        for (int g = 0; g < 2; ++g) acc[i][f][j][g] = (f32x4){0.f, 0.f, 0.f, 0.f};

  bf16x8 a_[4][2], b0_[2][2], b1_[2][2];

  // ---- prologue: tile 0 -> slot 0 (order Ah0, Bh0, Bh1, Ah1) ----
  STAGE_A(0, 0, 0);
  STAGE_B(0, 0, 0);
  STAGE_B(0, 1, 0);
  STAGE_A(0, 1, 0);
  VMCNT(4);              // Ah0,Bh0 resident; Bh1,Ah1 may still be in flight
  BARR;

  // ---- main loop: tiles 0..14 compute, tile t+1 staged one phase per phase ----
#pragma unroll 1
  for (int kt = 0; kt < 15; ++kt) {
    const int s  = kt & 1;
    const int so = s ^ 1;

    // phase 0: Q(mh0,nh0) ; stage A(t+1)h0
    LDA_HALF(s, 0);
    LDB_HALF(s, 0, b0_);
    STAGE_A(so, 0, kt + 1);
    VMCNT(4);
    BARR;
    MFMAQ(0, 0, b0_);
    BARR;

    // phase 1: Q(mh0,nh1) ; stage B(t+1)h0
    LDB_HALF(s, 1, b1_);
    STAGE_B(so, 0, kt + 1);
    VMCNT(4);
    BARR;
    MFMAQ(0, 1, b1_);
    BARR;

    // phase 2: Q(mh1,nh0) ; stage B(t+1)h1
    LDA_HALF(s, 1);
    STAGE_B(so, 1, kt + 1);
    VMCNT(4);
    BARR;
    MFMAQ(1, 0, b0_);
    BARR;

    // phase 3: Q(mh1,nh1) ; stage A(t+1)h1
    STAGE_A(so, 1, kt + 1);
    VMCNT(4);
    BARR;
    MFMAQ(1, 1, b1_);
    BARR;
  }

  // ---- peeled tile 15 (slot 1): drain 2 -> 0 ----
  LDA_HALF(1, 0);
  LDB_HALF(1, 0, b0_);
  VMCNT(2);              // Bh1(15) resident (only Ah1 may remain in flight)
  BARR;
  MFMAQ(0, 0, b0_);
  BARR;

  LDB_HALF(1, 1, b1_);
  VMCNT(0);              // Ah1(15) resident
  BARR;
  MFMAQ(0, 1, b1_);
  BARR;

  LDA_HALF(1, 1);
  MFMAQ(1, 0, b0_);
  MFMAQ(1, 1, b1_);

  // ---- epilogue: bias + fp8 quantize, write qT8[m][n] ----
#pragma unroll
  for (int mh = 0; mh < 2; ++mh)
#pragma unroll
    for (int f = 0; f < 4; ++f)
#pragma unroll
      for (int r = 0; r < 4; ++r) {
        const int m = m0 + mh * 128 + wm2 + f * 16 + quad * 4 + r;
        const float bv = bias[m];
        unsigned char* row = qT8 + (size_t)m * 16384 + n0;
#pragma unroll
        for (int nh = 0; nh < 2; ++nh)
#pragma unroll
          for (int g = 0; g < 2; ++g)
            row[nh * 128 + wn2 + g * 16 + lrow] = f2fp8(acc[mh][f][nh][g][r] + bv);
      }

#undef STAGE_A
#undef STAGE_B
#undef LDA_HALF
#undef LDB_HALF
#undef MFMAQ
}

// ------- fallback gemm_q (fused fp32->bf16 inline), used if ws too small -------
__global__ __launch_bounds__(256) void gemm_q_fused(
    const float* __restrict__ Wq, const float* __restrict__ V,
    const float* __restrict__ bias, unsigned char* __restrict__ qT8)
{
  __shared__ unsigned short As[128 * 32];
  __shared__ unsigned short Bs[128 * 32];

  const int m0 = blockIdx.y * 128;
  const int n0 = blockIdx.x * 128;
  const int t    = threadIdx.x;
  const int lane = t & 63;
  const int wave = t >> 6;
  const int wm = (wave >> 1) * 64;
  const int wn = (wave & 1) * 64;
  const int quad = lane >> 4;
  const int lrow = lane & 15;

  const int sr = t >> 1;
  const int sc = (t & 1) << 4;
  const float* gA = Wq + (size_t)(m0 + sr) * 1024 + sc;
  const float* gB = V  + (size_t)(n0 + sr) * 1024 + sc;

  f32x4 acc[4][4];
#pragma unroll
  for (int i = 0; i < 4; ++i)
#pragma unroll
    for (int j = 0; j < 4; ++j) acc[i][j] = (f32x4){0.f, 0.f, 0.f, 0.f};

  for (int k0 = 0; k0 < 1024; k0 += 32) {
    const float4* a4 = (const float4*)(gA + k0);
    const float4* b4 = (const float4*)(gB + k0);
    float4 av0 = a4[0], av1 = a4[1], av2 = a4[2], av3 = a4[3];
    float4 bv0 = b4[0], bv1 = b4[1], bv2 = b4[2], bv3 = b4[3];
    *(u16x8*)&As[sr * 32 + sc]     = pack8(av0, av1);
    *(u16x8*)&As[sr * 32 + sc + 8] = pack8(av2, av3);
    *(u16x8*)&Bs[sr * 32 + sc]     = pack8(bv0, bv1);
    *(u16x8*)&Bs[sr * 32 + sc + 8] = pack8(bv2, bv3);
    __syncthreads();

    bf16x8 af[4], bfr[4];
#pragma unroll
    for (int i = 0; i < 4; ++i)
      af[i] = *(const bf16x8*)&As[(wm + i * 16 + lrow) * 32 + quad * 8];
#pragma unroll
    for (int j = 0; j < 4; ++j)
      bfr[j] = *(const bf16x8*)&Bs[(wn + j * 16 + lrow) * 32 + quad * 8];
#pragma unroll
    for (int i = 0; i < 4; ++i)
#pragma unroll
      for (int j = 0; j < 4; ++j)
        acc[i][j] = __builtin_amdgcn_mfma_f32_16x16x32_bf16(af[i], bfr[j], acc[i][j], 0, 0, 0);
    __syncthreads();
  }

#pragma unroll
  for (int i = 0; i < 4; ++i) {
    const int mb = m0 + wm + i * 16 + quad * 4;
#pragma unroll
    for (int r = 0; r < 4; ++r) {
      const float bv = bias[mb + r];
#pragma unroll
      for (int j = 0; j < 4; ++j) {
        const int n = n0 + wn + j * 16 + lrow;
        qT8[(size_t)(mb + r) * 16384 + n] = f2fp8(acc[i][j][r] + bv);
      }
    }
  }
}

// ---------- syrk_half8: fp8, BK=128, dbuf 2-phase, batch->XCD swizzle ----------
// qT8 fp8 [1024][16384]; batch bb cols [bb*2048,+2048) = 2 MiB -> fits ONE
// XCD's 4 MiB L2. blockIdx.x in [0,576): bb = bid&7 so all 72 blocks of batch
// bb land on XCD bb -> after warmup all qT8 reads are L2 hits.
// id2=bid>>3: pair=id2>>1 (ty<=tx over 8 128-tiles), yh=id2&1.
// FULL K=2048 (relu nonlinear -> K-split illegal).
__global__ __launch_bounds__(256) void syrk_half8(
    const unsigned char* __restrict__ qT8, const float* __restrict__ W,
    float* __restrict__ out)
{
  __shared__ unsigned char As[2][128 * 128];  // 32 KB
  __shared__ unsigned char Bs[2][64 * 128];   // 16 KB

  const int bb   = blockIdx.x & 7;
  const int id2  = blockIdx.x >> 3;           // 0..71
  const int pair = id2 >> 1;
  const int yh   = id2 & 1;
  int tx = 0;
  while ((tx + 1) * (tx + 2) / 2 <= pair) ++tx;
  const int ty = pair - tx * (tx + 1) / 2;
  const int x0 = tx * 128;
  const int y0 = ty * 128 + yh * 64;
  const bool diag = (tx == ty);

  const int t    = threadIdx.x;
  const int lane = t & 63;
  const int wave = t >> 6;
  const int wm = (wave >> 1) * 64;   // x offset of wave: 0 or 64
  const int wn = (wave & 1) * 32;    // y offset of wave: 0 or 32
  const int quad = lane >> 4;
  const int lrow = lane & 15;

  // staging: issue p covers rows p*32 + (t>>3); global 16B chunk
  // (t&7)^(row&7) lands at LDS slot t&7.
  const int srow = t >> 3;                              // 0..31
  const int g16  = (t & 7) ^ (srow & 7);
  const size_t cb = (size_t)bb * 2048 + g16 * 16;
  const unsigned char* gA = qT8 + (size_t)(x0 + srow) * 16384 + cb;
  const unsigned char* gB = qT8 + (size_t)(y0 + srow) * 16384 + cb;

#define SSTAGE(SLOT, KT) do { \
  _Pragma("unroll") for (int p = 0; p < 4; ++p) \
    async16(&As[SLOT][p * 4096 + t * 16], gA + (size_t)p * 32 * 16384 + (KT) * 128); \
  _Pragma("unroll") for (int p = 0; p < 2; ++p) \
    async16(&Bs[SLOT][p * 4096 + t * 16], gB + (size_t)p * 32 * 16384 + (KT) * 128); \
} while (0)

#define SYRK_COMPUTE(S) do { \
  _Pragma("unroll") for (int kk = 0; kk < 4; ++kk) { \
    const int c = kk * 4 + quad; \
    const int off = (((c >> 1) ^ (lrow & 7)) << 4) + (c & 1) * 8; \
    i64 af[4], bfr[2]; \
    _Pragma("unroll") for (int i = 0; i < 4; ++i) \
      af[i] = *(const i64*)&As[S][(wm + i * 16 + lrow) * 128 + off]; \
    _Pragma("unroll") for (int j = 0; j < 2; ++j) \
      bfr[j] = *(const i64*)&Bs[S][(wn + j * 16 + lrow) * 128 + off]; \
    _Pragma("unroll") for (int i = 0; i < 4; ++i) \
      _Pragma("unroll") for (int j = 0; j < 2; ++j) \
        acc[i][j] = __builtin_amdgcn_mfma_f32_16x16x32_fp8_fp8(af[i], bfr[j], acc[i][j], 0, 0, 0); \
  } \
} while (0)

  f32x4 acc[4][2];
#pragma unroll
  for (int i = 0; i < 4; ++i)
#pragma unroll
    for (int j = 0; j < 2; ++j) acc[i][j] = (f32x4){0.f, 0.f, 0.f, 0.f};

  // prologue: stage tile 0 -> slot 0 (6 insts outstanding)
  SSTAGE(0, 0);

#pragma unroll 1
  for (int kt = 0; kt < 15; ++kt) {
    const int s = kt & 1;
    SSTAGE(s ^ 1, kt + 1);   // 6 insts; tile t's 6 may still be in flight
    VMCNT(6);                // completes tile t, leaves tile t+1 in flight
    BARR;                    // all waves' tile-t stages now visible
    SYRK_COMPUTE(s);
    BARR;                    // reads done before next iter overwrites slot s
  }

  // peeled kt=15 (slot 1): drain
  VMCNT(0);
  BARR;
  SYRK_COMPUTE(1);

#undef SSTAGE
#undef SYRK_COMPUTE

  float* ob = out + bb * 1024;

  // row pass: out[x] += sum_y relu(C[x,y]) * W[y]   (partial over this y-half)
  float wv[2];
#pragma unroll
  for (int j = 0; j < 2; ++j) wv[j] = W[y0 + wn + j * 16 + lrow];

#pragma unroll
  for (int i = 0; i < 4; ++i) {
#pragma unroll
    for (int r = 0; r < 4; ++r) {
      float p = 0.f;
#pragma unroll
      for (int j = 0; j < 2; ++j) {
        float v = acc[i][j][r];
        v = v > 0.f ? v : 0.f;
        p += v * wv[j];
      }
#pragma unroll
      for (int off = 1; off < 16; off <<= 1) p += __shfl_xor(p, off, 64);
      if (lrow == 0)
        atomicAdd(&ob[x0 + wm + i * 16 + quad * 4 + r], p);
    }
  }

  // col pass (off-diagonal pairs only): out[y] += sum_x relu(C[x,y]) * W[x]
  if (!diag) {
    float wx[4][4];
#pragma unroll
    for (int i = 0; i < 4; ++i)
#pragma unroll
      for (int r = 0; r < 4; ++r)
        wx[i][r] = W[x0 + wm + i * 16 + quad * 4 + r];

#pragma unroll
    for (int j = 0; j < 2; ++j) {
      float pc = 0.f;
#pragma unroll
      for (int i = 0; i < 4; ++i)
#pragma unroll
        for (int r = 0; r < 4; ++r) {
          float v = acc[i][j][r];
          v = v > 0.f ? v : 0.f;
          pc += v * wx[i][r];
        }
      pc += __shfl_xor(pc, 16, 64);
      pc += __shfl_xor(pc, 32, 64);
      if (quad == 0)
        atomicAdd(&ob[y0 + wn + j * 16 + lrow], pc);
    }
  }
}

extern "C" void kernel_launch(void* const* d_in, const int* in_sizes, int n_in,
                              void* d_out, int out_size, void* d_ws, size_t ws_size,
                              hipStream_t stream) {
  const float* vec   = (const float*)d_in[0];  // [8,2048,1024]
  const float* wq_w  = (const float*)d_in[1];  // [1024,1024]
  const float* wq_b  = (const float*)d_in[2];  // [1024]
  const float* lin_w = (const float*)d_in[3];  // [1,1024]
  const float* lin_b = (const float*)d_in[4];  // [1]
  float* out = (float*)d_out;                  // [8,1024]

  unsigned char* qT8 = (unsigned char*)d_ws;                       // 16 MiB
  const size_t need = (size_t)(16 + 32 + 2) * 1024 * 1024;

  if (ws_size >= need) {
    unsigned short* vecbf = (unsigned short*)((char*)d_ws + (size_t)16 * 1024 * 1024); // 32 MiB
    unsigned short* wqbf  = vecbf + (size_t)16 * 1024 * 1024;                          // 2 MiB
    prep<<<dim3(8192 + 512), dim3(256), 0, stream>>>(vec, vecbf, wq_w, wqbf, lin_b, out);
    gemm_q8p<<<dim3(64, 4), dim3(512), 0, stream>>>(wqbf, vecbf, wq_b, qT8);
  } else {
    init_out<<<dim3(32), dim3(256), 0, stream>>>(out, lin_b);
    gemm_q_fused<<<dim3(128, 8), dim3(256), 0, stream>>>(wq_w, vec, wq_b, qT8);
  }
  syrk_half8<<<dim3(576), dim3(256), 0, stream>>>(qT8, lin_w, out);
}